// Round 2
// baseline (734.979 us; speedup 1.0000x reference)
//
#include <hip/hip_runtime.h>
#include <math.h>

#define N_DIM 32
#define C_DIM 512
#define K_DIM 64
#define P_DIM 3136
#define ABLK 49   // 3136 / 64 pixel-blocks for k_logits / asum partials

// ws layout (floats): wt 32768 | a_t 6422528 | asum 2048 | asum_part 100352 |
//                     gsum 32 | ssb 16384 | part S*1048576
// S=14 -> ~82.6 MB, S=7 -> ~54 MB, S=2 -> ~33 MB (selected from ws_size)

// ---------------- prep: wt[c][k] = conv_w[k][c] ----------------
__global__ __launch_bounds__(256) void k_prep(const float* __restrict__ conv_w,
                                              float* __restrict__ wt) {
    const int b = blockIdx.x, t = threadIdx.x;
#pragma unroll
    for (int r = 0; r < 4; ++r) {
        int idx = b * 1024 + r * 256 + t;      // 0..32767
        int c = idx >> 6, k = idx & 63;
        wt[idx] = conv_w[k * C_DIM + c];
    }
}

// ---------------- GEMM1 + softmax + asum partials: a_t[n][p][k] ----------------
// LDS-free main loop (prior versions were LDS-issue-bound: 53 LDS-cyc vs 14
// VALU-cyc per c per wave -> VALUBusy stuck ~33%). Operand sharing now comes
// from in-wave same-address broadcast through L1: tid = tp*8+tk, so the 8 tk
// lanes of a pixel group read identical x addresses (one L1 transaction) and
// w reads are 256B contiguous per wave (wt = 128 KB, L2-resident).
// Thread tile 4px x 8k = 32 FMA : 3 VMEM per c; depth-4 register prefetch;
// no barriers in the loop. Block = 128 thr (2 waves), 64 px; grid 49x32
// (3136 = 49*64 exact, no tail).
__global__ __launch_bounds__(128) void k_logits(const float* __restrict__ x,
                                                const float* __restrict__ wt,
                                                const float* __restrict__ bias,
                                                float* __restrict__ a_t,
                                                float* __restrict__ asum_part) {
    __shared__ float asl[2][64];
    const int tid = threadIdx.x;
    const int n    = blockIdx.y;
    const int pblk = blockIdx.x;           // 0..48
    const int tk = tid & 7;                // lane bits 0..2 -> k group
    const int tp = tid >> 3;               // 0..15 -> pixel group
    const int p0 = pblk * 64 + tp * 4;     // 4 contiguous pixels per thread

    float acc[4][8];
    {
        float4 b0 = *(const float4*)(bias + tk * 8);
        float4 b1 = *(const float4*)(bias + tk * 8 + 4);
        float br[8] = {b0.x, b0.y, b0.z, b0.w, b1.x, b1.y, b1.z, b1.w};
#pragma unroll
        for (int i = 0; i < 4; ++i)
#pragma unroll
            for (int j = 0; j < 8; ++j) acc[i][j] = br[j];
    }

    const float* xp = x + (size_t)n * C_DIM * P_DIM + p0;
    const float* wp = wt + tk * 8;

    // depth-4 register prefetch buffers
    float4 xb[4], wa[4], wb[4];
#pragma unroll
    for (int d = 0; d < 4; ++d) {
        xb[d] = *(const float4*)(xp + (size_t)d * P_DIM);
        wa[d] = *(const float4*)(wp + d * K_DIM);
        wb[d] = *(const float4*)(wp + d * K_DIM + 4);
    }

    for (int c = 0; c < C_DIM; c += 4) {
#pragma unroll
        for (int u = 0; u < 4; ++u) {
            float xr[4] = {xb[u].x, xb[u].y, xb[u].z, xb[u].w};
            float wr[8] = {wa[u].x, wa[u].y, wa[u].z, wa[u].w,
                           wb[u].x, wb[u].y, wb[u].z, wb[u].w};
            if (c + 4 + u < C_DIM) {                 // prefetch c+4+u
                xb[u] = *(const float4*)(xp + (size_t)(4 + u) * P_DIM);
                wa[u] = *(const float4*)(wp + (4 + u) * K_DIM);
                wb[u] = *(const float4*)(wp + (4 + u) * K_DIM + 4);
            }
#pragma unroll
            for (int i = 0; i < 4; ++i)
#pragma unroll
                for (int j = 0; j < 8; ++j)
                    acc[i][j] = fmaf(xr[i], wr[j], acc[i][j]);
        }
        xp += (size_t)4 * P_DIM;
        wp += 4 * K_DIM;
    }

    // softmax per pixel: 64 k live in the 8 tk lanes (xor 1,2,4)
    float sk[8] = {0.f, 0.f, 0.f, 0.f, 0.f, 0.f, 0.f, 0.f};
#pragma unroll
    for (int i = 0; i < 4; ++i) {
        float m = acc[i][0];
#pragma unroll
        for (int j = 1; j < 8; ++j) m = fmaxf(m, acc[i][j]);
        m = fmaxf(m, __shfl_xor(m, 1));
        m = fmaxf(m, __shfl_xor(m, 2));
        m = fmaxf(m, __shfl_xor(m, 4));
        float e[8], s = 0.f;
#pragma unroll
        for (int j = 0; j < 8; ++j) { e[j] = __expf(acc[i][j] - m); s += e[j]; }
        s += __shfl_xor(s, 1);
        s += __shfl_xor(s, 2);
        s += __shfl_xor(s, 4);
        const float inv = 1.0f / s;
        float4 o0, o1;
        o0.x = e[0] * inv; o0.y = e[1] * inv; o0.z = e[2] * inv; o0.w = e[3] * inv;
        o1.x = e[4] * inv; o1.y = e[5] * inv; o1.z = e[6] * inv; o1.w = e[7] * inv;
        float* ap = a_t + ((size_t)n * P_DIM + p0 + i) * K_DIM + tk * 8;
        *(float4*)ap = o0;
        *(float4*)(ap + 4) = o1;
        sk[0] += o0.x; sk[1] += o0.y; sk[2] += o0.z; sk[3] += o0.w;
        sk[4] += o1.x; sk[5] += o1.y; sk[6] += o1.z; sk[7] += o1.w;
    }
    // reduce over tp (lane bits 3,4,5), then across the 2 waves via LDS
#pragma unroll
    for (int j = 0; j < 8; ++j) {
        sk[j] += __shfl_xor(sk[j], 8);
        sk[j] += __shfl_xor(sk[j], 16);
        sk[j] += __shfl_xor(sk[j], 32);
    }
    const int lane = tid & 63, wid = tid >> 6;
    if (lane < 8) {
#pragma unroll
        for (int j = 0; j < 8; ++j) asl[wid][lane * 8 + j] = sk[j];
    }
    __syncthreads();
    if (tid < 64)
        asum_part[((size_t)n * ABLK + pblk) * K_DIM + tid] = asl[0][tid] + asl[1][tid];
}

// ---------------- asum[n][k] = sum_b asum_part[n][b][k] ----------------
__global__ __launch_bounds__(256) void k_red(const float* __restrict__ asum_part,
                                             float* __restrict__ asum) {
    const int idx = blockIdx.x * 256 + threadIdx.x;   // 0..2047
    const int n = idx >> 6, k = idx & 63;
    float s = 0.f;
#pragma unroll
    for (int b = 0; b < ABLK; ++b)
        s += asum_part[((size_t)n * ABLK + b) * K_DIM + k];
    asum[idx] = s;
}

// ---------------- GEMM2: part[s][n][c][k] = sum_{p in slice s} x[n][c][p]*a_t[n][p][k] ----
// block: 128c x 64k, 128 threads, 8x8/thread; plain stores (no atomics);
// register-prefetch double buffering over 16-p chunks.
__global__ __launch_bounds__(128) void k_gemm2(const float* __restrict__ x,
                                               const float* __restrict__ a_t,
                                               float* __restrict__ part,
                                               int pslice) {
    __shared__ float xs[16][132];   // [p][c], pad 128->132 (stores 2-way max)
    __shared__ float as[16][64];    // [p][k]
    const int tid = threadIdx.x;
    const int c0 = blockIdx.x * 128;
    const int n  = blockIdx.y;
    const int s  = blockIdx.z;
    const int p0 = s * pslice;
    const int tc = tid >> 3;        // 0..15 -> c = c0 + tc*8
    const int tk = tid & 7;         // 0..7  -> k = tk*8

    float acc[8][8];
#pragma unroll
    for (int i = 0; i < 8; ++i)
#pragma unroll
        for (int j = 0; j < 8; ++j) acc[i][j] = 0.f;

    const float* xb = x + ((size_t)n * C_DIM + c0) * P_DIM + p0;
    const float* ab = a_t + ((size_t)n * P_DIM + p0) * K_DIM;

    float4 xv[4], av[2];
#pragma unroll
    for (int i = 0; i < 4; ++i) {
        int f = tid + 128 * i;
        xv[i] = *(const float4*)(xb + (size_t)(f >> 2) * P_DIM + (f & 3) * 4);
    }
#pragma unroll
    for (int i = 0; i < 2; ++i) {
        int f = tid + 128 * i;
        av[i] = *(const float4*)(ab + (size_t)(f >> 4) * K_DIM + (f & 15) * 4);
    }

    for (int pb = 0; pb < pslice; pb += 16) {
        __syncthreads();
#pragma unroll
        for (int i = 0; i < 4; ++i) {
            int f = tid + 128 * i;
            int c = f >> 2, pe = (f & 3) * 4;
            xs[pe + 0][c] = xv[i].x;
            xs[pe + 1][c] = xv[i].y;
            xs[pe + 2][c] = xv[i].z;
            xs[pe + 3][c] = xv[i].w;
        }
#pragma unroll
        for (int i = 0; i < 2; ++i) {
            int f = tid + 128 * i;
            *(float4*)&as[f >> 4][(f & 15) * 4] = av[i];
        }
        __syncthreads();

        if (pb + 16 < pslice) {
            const float* xc = xb + pb + 16;
            const float* ac = ab + (size_t)(pb + 16) * K_DIM;
#pragma unroll
            for (int i = 0; i < 4; ++i) {
                int f = tid + 128 * i;
                xv[i] = *(const float4*)(xc + (size_t)(f >> 2) * P_DIM + (f & 3) * 4);
            }
#pragma unroll
            for (int i = 0; i < 2; ++i) {
                int f = tid + 128 * i;
                av[i] = *(const float4*)(ac + (size_t)(f >> 4) * K_DIM + (f & 15) * 4);
            }
        }

#pragma unroll 4
        for (int p = 0; p < 16; ++p) {
            float4 x0 = *(const float4*)&xs[p][tc * 8];
            float4 x1 = *(const float4*)&xs[p][tc * 8 + 4];
            float4 a0 = *(const float4*)&as[p][tk * 8];
            float4 a1 = *(const float4*)&as[p][tk * 8 + 4];
            float xr[8] = {x0.x, x0.y, x0.z, x0.w, x1.x, x1.y, x1.z, x1.w};
            float ar[8] = {a0.x, a0.y, a0.z, a0.w, a1.x, a1.y, a1.z, a1.w};
#pragma unroll
            for (int i = 0; i < 8; ++i)
#pragma unroll
                for (int j = 0; j < 8; ++j)
                    acc[i][j] = fmaf(xr[i], ar[j], acc[i][j]);
        }
    }

    float* po = part + (((size_t)s * N_DIM + n) * C_DIM + c0 + tc * 8) * K_DIM + tk * 8;
#pragma unroll
    for (int i = 0; i < 8; ++i) {
        float4 o0, o1;
        o0.x = acc[i][0]; o0.y = acc[i][1]; o0.z = acc[i][2]; o0.w = acc[i][3];
        o1.x = acc[i][4]; o1.y = acc[i][5]; o1.z = acc[i][6]; o1.w = acc[i][7];
        *(float4*)&po[(size_t)i * K_DIM] = o0;
        *(float4*)&po[(size_t)i * K_DIM + 4] = o1;
    }
}

// ---------------- slice-reduce + subtract + intra-norm over k; ss -> ssb (no atomics) ----
template <int S>
__global__ __launch_bounds__(256) void k_intra(const float* __restrict__ part,
                                               const float* __restrict__ cent,
                                               const float* __restrict__ asum,
                                               float* __restrict__ out,
                                               float* __restrict__ ssb) {
    const int w = (blockIdx.x * 256 + threadIdx.x) >> 6;  // (n,c) wave id
    const int lane = threadIdx.x & 63;
    const int n = w >> 9;
    const int c = w & 511;
    const size_t off = ((size_t)n * C_DIM + c) * K_DIM + lane;
    const size_t stride = (size_t)N_DIM * C_DIM * K_DIM;

    float v = 0.f;
#pragma unroll
    for (int s = 0; s < S; ++s) v += part[s * stride + off];
    // cent_r[c][k] = centroids_flat[c*64 + k] (row-major reshape, NOT transpose)
    v -= cent[c * K_DIM + lane] * asum[n * K_DIM + lane];

    float ss = v * v;
#pragma unroll
    for (int o = 32; o > 0; o >>= 1) ss += __shfl_xor(ss, o);

    const float denom = fmaxf(sqrtf(ss), 1e-12f);
    out[off] = v / denom;
    if (lane == 0) ssb[w] = ss / (denom * denom);   // == clipped ratio, sums to gsum
}

// ---------------- gsum[n] = sum_c ssb[n][c] ----------------
__global__ __launch_bounds__(256) void k_gsum(const float* __restrict__ ssb,
                                              float* __restrict__ gsum) {
    const int n = blockIdx.x, t = threadIdx.x;
    float s = ssb[n * C_DIM + t] + ssb[n * C_DIM + t + 256];
    __shared__ float red[256];
    red[t] = s;
    __syncthreads();
    for (int o = 128; o > 0; o >>= 1) {
        if (t < o) red[t] += red[t + o];
        __syncthreads();
    }
    if (t == 0) gsum[n] = red[0];
}

// ---------------- final global L2 normalization ----------------
__global__ __launch_bounds__(256) void k_final(float* __restrict__ out,
                                               const float* __restrict__ gsum) {
    const size_t i = (size_t)blockIdx.x * 256 + threadIdx.x;  // 0 .. 2^20-1
    const int n = (int)(i >> 15);                             // C*K = 32768
    const float g = sqrtf(gsum[n]);
    out[i] = out[i] / fmaxf(g, 1e-12f);
}

extern "C" void kernel_launch(void* const* d_in, const int* in_sizes, int n_in,
                              void* d_out, int out_size, void* d_ws, size_t ws_size,
                              hipStream_t stream) {
    const float* x      = (const float*)d_in[0];  // (32,512,56,56)
    const float* cent   = (const float*)d_in[1];  // (64,512) flat
    const float* conv_w = (const float*)d_in[2];  // (64,512)
    const float* conv_b = (const float*)d_in[3];  // (64,)

    float* ws    = (float*)d_ws;
    float* wt    = ws;                                     // 32768
    float* a_t   = wt + 32768;                             // 32*3136*64
    float* asum  = a_t + (size_t)N_DIM * P_DIM * K_DIM;    // 2048
    float* apart = asum + 2048;                            // 32*49*64 = 100352
    float* gsum  = apart + (size_t)N_DIM * ABLK * K_DIM;   // 32
    float* ssb   = gsum + 32;                              // 16384
    float* part  = ssb + 16384;                            // S * 1048576
    float* out   = (float*)d_out;

    const size_t base_f = (size_t)(part - ws);
    const size_t cxk = (size_t)N_DIM * C_DIM * K_DIM;      // 1048576
    int S = 14;
    if (ws_size < (base_f + 14 * cxk) * 4) S = 7;
    if (ws_size < (base_f + 7 * cxk) * 4) S = 2;
    const int pslice = P_DIM / S;

    hipLaunchKernelGGL(k_prep,   dim3(32),        dim3(256), 0, stream, conv_w, wt);
    hipLaunchKernelGGL(k_logits, dim3(ABLK, 32),  dim3(128), 0, stream, x, wt, conv_b, a_t, apart);
    hipLaunchKernelGGL(k_red,    dim3(8),         dim3(256), 0, stream, apart, asum);
    hipLaunchKernelGGL(k_gemm2,  dim3(4, 32, S),  dim3(128), 0, stream, x, a_t, part, pslice);
    if (S == 14)
        hipLaunchKernelGGL(k_intra<14>, dim3(4096), dim3(256), 0, stream, part, cent, asum, out, ssb);
    else if (S == 7)
        hipLaunchKernelGGL(k_intra<7>,  dim3(4096), dim3(256), 0, stream, part, cent, asum, out, ssb);
    else
        hipLaunchKernelGGL(k_intra<2>,  dim3(4096), dim3(256), 0, stream, part, cent, asum, out, ssb);
    hipLaunchKernelGGL(k_gsum,   dim3(32),        dim3(256), 0, stream, ssb, gsum);
    hipLaunchKernelGGL(k_final,  dim3(4096),      dim3(256), 0, stream, out, gsum);
}

// Round 3
// 624.677 us; speedup vs baseline: 1.1766x; 1.1766x over previous
//
#include <hip/hip_runtime.h>
#include <math.h>

#define N_DIM 32
#define C_DIM 512
#define K_DIM 64
#define P_DIM 3136

// ws layout (floats): wt 32768 | a_t 6422528 | asum 2048 | asum_part 28672 |
//                     gsum 32 | ssb 16384 | part S*1048576
// S=14 -> 84.8 MB, S=7 -> 55.4 MB, S=2 -> 34.1 MB (selected from ws_size)

// ---------------- prep: wt[c][k] = conv_w[k][c] ----------------
__global__ __launch_bounds__(256) void k_prep(const float* __restrict__ conv_w,
                                              float* __restrict__ wt) {
    const int b = blockIdx.x, t = threadIdx.x;
#pragma unroll
    for (int r = 0; r < 4; ++r) {
        int idx = b * 1024 + r * 256 + t;      // 0..32767
        int c = idx >> 6, k = idx & 63;
        wt[idx] = conv_w[k * C_DIM + c];
    }
}

// ---------------- GEMM1 + softmax: a_t[n][p][k] ----------------
// lane = pixel; all 64 k accumulators in VGPRs. Per channel: ONE ds_read_b32
// (x, per-lane, 2-way bank = free) feeds 64 FMAs; w row is wave-uniform ->
// scalar s_load (SMEM pipe, L2-hot 128KB wt), v_fmac v,s,v.
// Prior designs: LDS-issue-bound (65 LDS-cyc vs 112 FMA-cyc per wave, 4 waves
// share 1 LDS -> 43% cap) or latency-bound (LDS-free). This puts LDS demand at
// 4x5.8=23 cyc per 128 FMA-cyc per CU.
// 1-wave blocks: no __syncthreads (no vmcnt(0) barrier drain); x staged in
// 16-channel double-buffered LDS chunks, staging hidden under ~2k-cycle compute.
// Softmax fully lane-local (no shuffles). Grid 49x32 = 1568 waves.
__global__ __launch_bounds__(64) void k_logits(const float* __restrict__ x,
                                               const float* __restrict__ wt,
                                               const float* __restrict__ bias,
                                               float* __restrict__ a_t) {
    __shared__ float xs[2][16][64];        // 8 KB double buffer
    const int lane = threadIdx.x;          // 0..63 = pixel within block
    const int n    = blockIdx.y;
    const int pblk = blockIdx.x;           // 0..48
    const int p    = pblk * 64 + lane;

    float acc[64];
#pragma unroll
    for (int k = 0; k < 64; ++k) acc[k] = bias[k];   // uniform -> s_load + v_mov

    const float* xb = x + (size_t)n * C_DIM * P_DIM + pblk * 64;
    const int r0 = lane >> 4;              // 0..3   (row within 4-row group)
    const int q0 = (lane & 15) * 4;        // 0..60  (col, float4 granularity)

    float4 xv[4];
#define STAGE_LOAD(c0_) do {                                                     \
    _Pragma("unroll")                                                            \
    for (int j = 0; j < 4; ++j)                                                  \
        xv[j] = *(const float4*)(xb + (size_t)((c0_) + j * 4 + r0) * P_DIM + q0);\
    } while (0)
#define STAGE_WRITE(buf_) do {                                                   \
    _Pragma("unroll")                                                            \
    for (int j = 0; j < 4; ++j)                                                  \
        *(float4*)&xs[buf_][j * 4 + r0][q0] = xv[j];                             \
    } while (0)

    STAGE_LOAD(0);
    STAGE_WRITE(0);
    STAGE_LOAD(16);

    for (int c0 = 0; c0 < C_DIM; c0 += 16) {
        const int buf = (c0 >> 4) & 1;
        if (c0 + 16 < C_DIM) {
            STAGE_WRITE(buf ^ 1);                  // xv (chunk c0+16) -> other buf
            if (c0 + 32 < C_DIM) STAGE_LOAD(c0 + 32);
        }
#pragma unroll
        for (int cc = 0; cc < 16; ++cc) {
            const float xval = xs[buf][cc][lane];  // 1 ds_read_b32 per 64 FMA
            const float* wrow = wt + (size_t)(c0 + cc) * K_DIM;  // uniform
#pragma unroll
            for (int k = 0; k < 64; ++k)
                acc[k] = fmaf(xval, wrow[k], acc[k]);
        }
    }
#undef STAGE_LOAD
#undef STAGE_WRITE

    // lane-local softmax over the 64 in-register logits
    float m = acc[0];
#pragma unroll
    for (int k = 1; k < 64; ++k) m = fmaxf(m, acc[k]);
    float s = 0.f;
#pragma unroll
    for (int k = 0; k < 64; ++k) { acc[k] = __expf(acc[k] - m); s += acc[k]; }
    const float inv = 1.0f / s;

    float* ap = a_t + ((size_t)n * P_DIM + p) * K_DIM;
#pragma unroll
    for (int k = 0; k < 64; k += 4) {
        float4 o;
        o.x = acc[k] * inv; o.y = acc[k + 1] * inv;
        o.z = acc[k + 2] * inv; o.w = acc[k + 3] * inv;
        *(float4*)(ap + k) = o;
    }
}

// ---------------- asum partials from a_t: apart[n][py][k], py<14 (224 px each) ----
__global__ __launch_bounds__(256) void k_asum(const float* __restrict__ a_t,
                                              float* __restrict__ apart) {
    const int t  = threadIdx.x;
    const int py = blockIdx.x;             // 0..13
    const int n  = blockIdx.y;
    const int k  = t & 63, pg = t >> 6;    // 4 p-lanes per k
    const float* ab = a_t + ((size_t)n * P_DIM + py * 224) * K_DIM + k;
    float s = 0.f;
#pragma unroll 8
    for (int i = 0; i < 56; ++i)
        s += ab[(size_t)(pg + 4 * i) * K_DIM];
    __shared__ float red[4][64];
    red[pg][k] = s;
    __syncthreads();
    if (t < 64)
        apart[((size_t)n * 14 + py) * K_DIM + t] =
            red[0][t] + red[1][t] + red[2][t] + red[3][t];
}

// ---------------- asum[n][k] = sum_b asum_part[n][b][k] ----------------
__global__ __launch_bounds__(256) void k_red(const float* __restrict__ asum_part,
                                             float* __restrict__ asum) {
    const int idx = blockIdx.x * 256 + threadIdx.x;   // 0..2047
    const int n = idx >> 6, k = idx & 63;
    float s = 0.f;
#pragma unroll
    for (int b = 0; b < 14; ++b)
        s += asum_part[((size_t)n * 14 + b) * K_DIM + k];
    asum[idx] = s;
}

// ---------------- GEMM2: part[s][n][c][k] = sum_{p in slice s} x[n][c][p]*a_t[n][p][k] ----
// block: 128c x 64k, 128 threads, 8x8/thread; plain stores (no atomics);
// register-prefetch double buffering over 16-p chunks.
__global__ __launch_bounds__(128) void k_gemm2(const float* __restrict__ x,
                                               const float* __restrict__ a_t,
                                               float* __restrict__ part,
                                               int pslice) {
    __shared__ float xs[16][132];   // [p][c], pad 128->132 (stores 2-way max)
    __shared__ float as[16][64];    // [p][k]
    const int tid = threadIdx.x;
    const int c0 = blockIdx.x * 128;
    const int n  = blockIdx.y;
    const int s  = blockIdx.z;
    const int p0 = s * pslice;
    const int tc = tid >> 3;        // 0..15 -> c = c0 + tc*8
    const int tk = tid & 7;         // 0..7  -> k = tk*8

    float acc[8][8];
#pragma unroll
    for (int i = 0; i < 8; ++i)
#pragma unroll
        for (int j = 0; j < 8; ++j) acc[i][j] = 0.f;

    const float* xb = x + ((size_t)n * C_DIM + c0) * P_DIM + p0;
    const float* ab = a_t + ((size_t)n * P_DIM + p0) * K_DIM;

    float4 xv[4], av[2];
#pragma unroll
    for (int i = 0; i < 4; ++i) {
        int f = tid + 128 * i;
        xv[i] = *(const float4*)(xb + (size_t)(f >> 2) * P_DIM + (f & 3) * 4);
    }
#pragma unroll
    for (int i = 0; i < 2; ++i) {
        int f = tid + 128 * i;
        av[i] = *(const float4*)(ab + (size_t)(f >> 4) * K_DIM + (f & 15) * 4);
    }

    for (int pb = 0; pb < pslice; pb += 16) {
        __syncthreads();
#pragma unroll
        for (int i = 0; i < 4; ++i) {
            int f = tid + 128 * i;
            int c = f >> 2, pe = (f & 3) * 4;
            xs[pe + 0][c] = xv[i].x;
            xs[pe + 1][c] = xv[i].y;
            xs[pe + 2][c] = xv[i].z;
            xs[pe + 3][c] = xv[i].w;
        }
#pragma unroll
        for (int i = 0; i < 2; ++i) {
            int f = tid + 128 * i;
            *(float4*)&as[f >> 4][(f & 15) * 4] = av[i];
        }
        __syncthreads();

        if (pb + 16 < pslice) {
            const float* xc = xb + pb + 16;
            const float* ac = ab + (size_t)(pb + 16) * K_DIM;
#pragma unroll
            for (int i = 0; i < 4; ++i) {
                int f = tid + 128 * i;
                xv[i] = *(const float4*)(xc + (size_t)(f >> 2) * P_DIM + (f & 3) * 4);
            }
#pragma unroll
            for (int i = 0; i < 2; ++i) {
                int f = tid + 128 * i;
                av[i] = *(const float4*)(ac + (size_t)(f >> 4) * K_DIM + (f & 15) * 4);
            }
        }

#pragma unroll 4
        for (int p = 0; p < 16; ++p) {
            float4 x0 = *(const float4*)&xs[p][tc * 8];
            float4 x1 = *(const float4*)&xs[p][tc * 8 + 4];
            float4 a0 = *(const float4*)&as[p][tk * 8];
            float4 a1 = *(const float4*)&as[p][tk * 8 + 4];
            float xr[8] = {x0.x, x0.y, x0.z, x0.w, x1.x, x1.y, x1.z, x1.w};
            float ar[8] = {a0.x, a0.y, a0.z, a0.w, a1.x, a1.y, a1.z, a1.w};
#pragma unroll
            for (int i = 0; i < 8; ++i)
#pragma unroll
                for (int j = 0; j < 8; ++j)
                    acc[i][j] = fmaf(xr[i], ar[j], acc[i][j]);
        }
    }

    float* po = part + (((size_t)s * N_DIM + n) * C_DIM + c0 + tc * 8) * K_DIM + tk * 8;
#pragma unroll
    for (int i = 0; i < 8; ++i) {
        float4 o0, o1;
        o0.x = acc[i][0]; o0.y = acc[i][1]; o0.z = acc[i][2]; o0.w = acc[i][3];
        o1.x = acc[i][4]; o1.y = acc[i][5]; o1.z = acc[i][6]; o1.w = acc[i][7];
        *(float4*)&po[(size_t)i * K_DIM] = o0;
        *(float4*)&po[(size_t)i * K_DIM + 4] = o1;
    }
}

// ---------------- slice-reduce + subtract + intra-norm over k; ss -> ssb (no atomics) ----
template <int S>
__global__ __launch_bounds__(256) void k_intra(const float* __restrict__ part,
                                               const float* __restrict__ cent,
                                               const float* __restrict__ asum,
                                               float* __restrict__ out,
                                               float* __restrict__ ssb) {
    const int w = (blockIdx.x * 256 + threadIdx.x) >> 6;  // (n,c) wave id
    const int lane = threadIdx.x & 63;
    const int n = w >> 9;
    const int c = w & 511;
    const size_t off = ((size_t)n * C_DIM + c) * K_DIM + lane;
    const size_t stride = (size_t)N_DIM * C_DIM * K_DIM;

    float v = 0.f;
#pragma unroll
    for (int s = 0; s < S; ++s) v += part[s * stride + off];
    // cent_r[c][k] = centroids_flat[c*64 + k] (row-major reshape, NOT transpose)
    v -= cent[c * K_DIM + lane] * asum[n * K_DIM + lane];

    float ss = v * v;
#pragma unroll
    for (int o = 32; o > 0; o >>= 1) ss += __shfl_xor(ss, o);

    const float denom = fmaxf(sqrtf(ss), 1e-12f);
    out[off] = v / denom;
    if (lane == 0) ssb[w] = ss / (denom * denom);   // == clipped ratio, sums to gsum
}

// ---------------- gsum[n] = sum_c ssb[n][c] ----------------
__global__ __launch_bounds__(256) void k_gsum(const float* __restrict__ ssb,
                                              float* __restrict__ gsum) {
    const int n = blockIdx.x, t = threadIdx.x;
    float s = ssb[n * C_DIM + t] + ssb[n * C_DIM + t + 256];
    __shared__ float red[256];
    red[t] = s;
    __syncthreads();
    for (int o = 128; o > 0; o >>= 1) {
        if (t < o) red[t] += red[t + o];
        __syncthreads();
    }
    if (t == 0) gsum[n] = red[0];
}

// ---------------- final global L2 normalization ----------------
__global__ __launch_bounds__(256) void k_final(float* __restrict__ out,
                                               const float* __restrict__ gsum) {
    const size_t i = (size_t)blockIdx.x * 256 + threadIdx.x;  // 0 .. 2^20-1
    const int n = (int)(i >> 15);                             // C*K = 32768
    const float g = sqrtf(gsum[n]);
    out[i] = out[i] / fmaxf(g, 1e-12f);
}

extern "C" void kernel_launch(void* const* d_in, const int* in_sizes, int n_in,
                              void* d_out, int out_size, void* d_ws, size_t ws_size,
                              hipStream_t stream) {
    const float* x      = (const float*)d_in[0];  // (32,512,56,56)
    const float* cent   = (const float*)d_in[1];  // (64,512) flat
    const float* conv_w = (const float*)d_in[2];  // (64,512)
    const float* conv_b = (const float*)d_in[3];  // (64,)

    float* ws    = (float*)d_ws;
    float* wt    = ws;                                     // 32768
    float* a_t   = wt + 32768;                             // 32*3136*64
    float* asum  = a_t + (size_t)N_DIM * P_DIM * K_DIM;    // 2048
    float* apart = asum + 2048;                            // 32*14*64 = 28672
    float* gsum  = apart + 28672;                          // 32
    float* ssb   = gsum + 32;                              // 16384
    float* part  = ssb + 16384;                            // S * 1048576
    float* out   = (float*)d_out;

    const size_t base_f = (size_t)(part - ws);
    const size_t cxk = (size_t)N_DIM * C_DIM * K_DIM;      // 1048576
    int S = 14;
    if (ws_size < (base_f + 14 * cxk) * 4) S = 7;
    if (ws_size < (base_f + 7 * cxk) * 4) S = 2;
    const int pslice = P_DIM / S;

    hipLaunchKernelGGL(k_prep,   dim3(32),        dim3(256), 0, stream, conv_w, wt);
    hipLaunchKernelGGL(k_logits, dim3(49, 32),    dim3(64),  0, stream, x, wt, conv_b, a_t);
    hipLaunchKernelGGL(k_asum,   dim3(14, 32),    dim3(256), 0, stream, a_t, apart);
    hipLaunchKernelGGL(k_red,    dim3(8),         dim3(256), 0, stream, apart, asum);
    hipLaunchKernelGGL(k_gemm2,  dim3(4, 32, S),  dim3(128), 0, stream, x, a_t, part, pslice);
    if (S == 14)
        hipLaunchKernelGGL(k_intra<14>, dim3(4096), dim3(256), 0, stream, part, cent, asum, out, ssb);
    else if (S == 7)
        hipLaunchKernelGGL(k_intra<7>,  dim3(4096), dim3(256), 0, stream, part, cent, asum, out, ssb);
    else
        hipLaunchKernelGGL(k_intra<2>,  dim3(4096), dim3(256), 0, stream, part, cent, asum, out, ssb);
    hipLaunchKernelGGL(k_gsum,   dim3(32),        dim3(256), 0, stream, ssb, gsum);
    hipLaunchKernelGGL(k_final,  dim3(4096),      dim3(256), 0, stream, out, gsum);
}

// Round 4
// 617.629 us; speedup vs baseline: 1.1900x; 1.0114x over previous
//
#include <hip/hip_runtime.h>
#include <math.h>

#define N_DIM 32
#define C_DIM 512
#define K_DIM 64
#define P_DIM 3136

// ws layout (floats): wt 32768 | a_t 6422528 | asum 2048 | asum_part 28672 |
//                     gsum 32 | ssb 16384 | part S*1048576
// S=14 -> 84.8 MB, S=7 -> 55.4 MB, S=2 -> 34.1 MB (selected from ws_size)

// ---------------- prep: wt[c][k] = conv_w[k][c] ----------------
__global__ __launch_bounds__(256) void k_prep(const float* __restrict__ conv_w,
                                              float* __restrict__ wt) {
    const int b = blockIdx.x, t = threadIdx.x;
#pragma unroll
    for (int r = 0; r < 4; ++r) {
        int idx = b * 1024 + r * 256 + t;      // 0..32767
        int c = idx >> 6, k = idx & 63;
        wt[idx] = conv_w[k * C_DIM + c];
    }
}

// ---------------- GEMM1 + softmax: a_t[n][p][k] ----------------
// lane = pixel; all 64 k accumulators in VGPRs. Per channel: ONE ds_read_b32
// (x, per-lane, 2-way bank = free) feeds 64 FMAs; w row is wave-uniform ->
// scalar s_load (SMEM pipe, L2-hot 128KB wt), v_fmac v,s,v.
// ROUND-3 BUG: __launch_bounds__(64) alone let the compiler target high
// occupancy -> VGPR_Count=48 -> acc[64] spilled to scratch (WRITE_SIZE showed
// +24MB of spill stores, VALUBusy 19%). Fix: (64, 1) = min 1 wave/EU, which
// permits up to 512 VGPRs; acc stays in registers.
// 1-wave blocks: no __syncthreads (wave-internal lgkmcnt ordering); x staged in
// 16-channel double-buffered LDS chunks, staging hidden under ~2k-cycle compute.
// Softmax fully lane-local (no shuffles). Grid 49x32 = 1568 waves.
__global__ __launch_bounds__(64, 1) void k_logits(const float* __restrict__ x,
                                                  const float* __restrict__ wt,
                                                  const float* __restrict__ bias,
                                                  float* __restrict__ a_t) {
    __shared__ float xs[2][16][64];        // 8 KB double buffer
    const int lane = threadIdx.x;          // 0..63 = pixel within block
    const int n    = blockIdx.y;
    const int pblk = blockIdx.x;           // 0..48
    const int p    = pblk * 64 + lane;

    float acc[64];
#pragma unroll
    for (int k = 0; k < 64; ++k) acc[k] = bias[k];   // uniform -> s_load + v_mov

    const float* xb = x + (size_t)n * C_DIM * P_DIM + pblk * 64;
    const int r0 = lane >> 4;              // 0..3   (row within 4-row group)
    const int q0 = (lane & 15) * 4;        // 0..60  (col, float4 granularity)

    float4 xv[4];
#define STAGE_LOAD(c0_) do {                                                     \
    _Pragma("unroll")                                                            \
    for (int j = 0; j < 4; ++j)                                                  \
        xv[j] = *(const float4*)(xb + (size_t)((c0_) + j * 4 + r0) * P_DIM + q0);\
    } while (0)
#define STAGE_WRITE(buf_) do {                                                   \
    _Pragma("unroll")                                                            \
    for (int j = 0; j < 4; ++j)                                                  \
        *(float4*)&xs[buf_][j * 4 + r0][q0] = xv[j];                             \
    } while (0)

    STAGE_LOAD(0);
    STAGE_WRITE(0);
    STAGE_LOAD(16);

    for (int c0 = 0; c0 < C_DIM; c0 += 16) {
        const int buf = (c0 >> 4) & 1;
        if (c0 + 16 < C_DIM) {
            STAGE_WRITE(buf ^ 1);                  // xv (chunk c0+16) -> other buf
            if (c0 + 32 < C_DIM) STAGE_LOAD(c0 + 32);
        }
#pragma unroll
        for (int cc = 0; cc < 16; ++cc) {
            const float xval = xs[buf][cc][lane];  // 1 ds_read_b32 per 64 FMA
            const float* wrow = wt + (size_t)(c0 + cc) * K_DIM;  // uniform
#pragma unroll
            for (int k = 0; k < 64; ++k)
                acc[k] = fmaf(xval, wrow[k], acc[k]);
        }
    }
#undef STAGE_LOAD
#undef STAGE_WRITE

    // lane-local softmax over the 64 in-register logits
    float m = acc[0];
#pragma unroll
    for (int k = 1; k < 64; ++k) m = fmaxf(m, acc[k]);
    float s = 0.f;
#pragma unroll
    for (int k = 0; k < 64; ++k) { acc[k] = __expf(acc[k] - m); s += acc[k]; }
    const float inv = 1.0f / s;

    float* ap = a_t + ((size_t)n * P_DIM + p) * K_DIM;
#pragma unroll
    for (int k = 0; k < 64; k += 4) {
        float4 o;
        o.x = acc[k] * inv; o.y = acc[k + 1] * inv;
        o.z = acc[k + 2] * inv; o.w = acc[k + 3] * inv;
        *(float4*)(ap + k) = o;
    }
}

// ---------------- asum partials from a_t: apart[n][py][k], py<14 (224 px each) ----
__global__ __launch_bounds__(256) void k_asum(const float* __restrict__ a_t,
                                              float* __restrict__ apart) {
    const int t  = threadIdx.x;
    const int py = blockIdx.x;             // 0..13
    const int n  = blockIdx.y;
    const int k  = t & 63, pg = t >> 6;    // 4 p-lanes per k
    const float* ab = a_t + ((size_t)n * P_DIM + py * 224) * K_DIM + k;
    float s = 0.f;
#pragma unroll 8
    for (int i = 0; i < 56; ++i)
        s += ab[(size_t)(pg + 4 * i) * K_DIM];
    __shared__ float red[4][64];
    red[pg][k] = s;
    __syncthreads();
    if (t < 64)
        apart[((size_t)n * 14 + py) * K_DIM + t] =
            red[0][t] + red[1][t] + red[2][t] + red[3][t];
}

// ---------------- asum[n][k] = sum_b asum_part[n][b][k] ----------------
__global__ __launch_bounds__(256) void k_red(const float* __restrict__ asum_part,
                                             float* __restrict__ asum) {
    const int idx = blockIdx.x * 256 + threadIdx.x;   // 0..2047
    const int n = idx >> 6, k = idx & 63;
    float s = 0.f;
#pragma unroll
    for (int b = 0; b < 14; ++b)
        s += asum_part[((size_t)n * 14 + b) * K_DIM + k];
    asum[idx] = s;
}

// ---------------- GEMM2: part[s][n][c][k] = sum_{p in slice s} x[n][c][p]*a_t[n][p][k] ----
// block: 128c x 64k, 128 threads, 8x8/thread; plain stores (no atomics);
// register-prefetch double buffering over 16-p chunks.
__global__ __launch_bounds__(128) void k_gemm2(const float* __restrict__ x,
                                               const float* __restrict__ a_t,
                                               float* __restrict__ part,
                                               int pslice) {
    __shared__ float xs[16][132];   // [p][c], pad 128->132 (stores 2-way max)
    __shared__ float as[16][64];    // [p][k]
    const int tid = threadIdx.x;
    const int c0 = blockIdx.x * 128;
    const int n  = blockIdx.y;
    const int s  = blockIdx.z;
    const int p0 = s * pslice;
    const int tc = tid >> 3;        // 0..15 -> c = c0 + tc*8
    const int tk = tid & 7;         // 0..7  -> k = tk*8

    float acc[8][8];
#pragma unroll
    for (int i = 0; i < 8; ++i)
#pragma unroll
        for (int j = 0; j < 8; ++j) acc[i][j] = 0.f;

    const float* xb = x + ((size_t)n * C_DIM + c0) * P_DIM + p0;
    const float* ab = a_t + ((size_t)n * P_DIM + p0) * K_DIM;

    float4 xv[4], av[2];
#pragma unroll
    for (int i = 0; i < 4; ++i) {
        int f = tid + 128 * i;
        xv[i] = *(const float4*)(xb + (size_t)(f >> 2) * P_DIM + (f & 3) * 4);
    }
#pragma unroll
    for (int i = 0; i < 2; ++i) {
        int f = tid + 128 * i;
        av[i] = *(const float4*)(ab + (size_t)(f >> 4) * K_DIM + (f & 15) * 4);
    }

    for (int pb = 0; pb < pslice; pb += 16) {
        __syncthreads();
#pragma unroll
        for (int i = 0; i < 4; ++i) {
            int f = tid + 128 * i;
            int c = f >> 2, pe = (f & 3) * 4;
            xs[pe + 0][c] = xv[i].x;
            xs[pe + 1][c] = xv[i].y;
            xs[pe + 2][c] = xv[i].z;
            xs[pe + 3][c] = xv[i].w;
        }
#pragma unroll
        for (int i = 0; i < 2; ++i) {
            int f = tid + 128 * i;
            *(float4*)&as[f >> 4][(f & 15) * 4] = av[i];
        }
        __syncthreads();

        if (pb + 16 < pslice) {
            const float* xc = xb + pb + 16;
            const float* ac = ab + (size_t)(pb + 16) * K_DIM;
#pragma unroll
            for (int i = 0; i < 4; ++i) {
                int f = tid + 128 * i;
                xv[i] = *(const float4*)(xc + (size_t)(f >> 2) * P_DIM + (f & 3) * 4);
            }
#pragma unroll
            for (int i = 0; i < 2; ++i) {
                int f = tid + 128 * i;
                av[i] = *(const float4*)(ac + (size_t)(f >> 4) * K_DIM + (f & 15) * 4);
            }
        }

#pragma unroll 4
        for (int p = 0; p < 16; ++p) {
            float4 x0 = *(const float4*)&xs[p][tc * 8];
            float4 x1 = *(const float4*)&xs[p][tc * 8 + 4];
            float4 a0 = *(const float4*)&as[p][tk * 8];
            float4 a1 = *(const float4*)&as[p][tk * 8 + 4];
            float xr[8] = {x0.x, x0.y, x0.z, x0.w, x1.x, x1.y, x1.z, x1.w};
            float ar[8] = {a0.x, a0.y, a0.z, a0.w, a1.x, a1.y, a1.z, a1.w};
#pragma unroll
            for (int i = 0; i < 8; ++i)
#pragma unroll
                for (int j = 0; j < 8; ++j)
                    acc[i][j] = fmaf(xr[i], ar[j], acc[i][j]);
        }
    }

    float* po = part + (((size_t)s * N_DIM + n) * C_DIM + c0 + tc * 8) * K_DIM + tk * 8;
#pragma unroll
    for (int i = 0; i < 8; ++i) {
        float4 o0, o1;
        o0.x = acc[i][0]; o0.y = acc[i][1]; o0.z = acc[i][2]; o0.w = acc[i][3];
        o1.x = acc[i][4]; o1.y = acc[i][5]; o1.z = acc[i][6]; o1.w = acc[i][7];
        *(float4*)&po[(size_t)i * K_DIM] = o0;
        *(float4*)&po[(size_t)i * K_DIM + 4] = o1;
    }
}

// ---------------- slice-reduce + subtract + intra-norm over k; ss -> ssb (no atomics) ----
template <int S>
__global__ __launch_bounds__(256) void k_intra(const float* __restrict__ part,
                                               const float* __restrict__ cent,
                                               const float* __restrict__ asum,
                                               float* __restrict__ out,
                                               float* __restrict__ ssb) {
    const int w = (blockIdx.x * 256 + threadIdx.x) >> 6;  // (n,c) wave id
    const int lane = threadIdx.x & 63;
    const int n = w >> 9;
    const int c = w & 511;
    const size_t off = ((size_t)n * C_DIM + c) * K_DIM + lane;
    const size_t stride = (size_t)N_DIM * C_DIM * K_DIM;

    float v = 0.f;
#pragma unroll
    for (int s = 0; s < S; ++s) v += part[s * stride + off];
    // cent_r[c][k] = centroids_flat[c*64 + k] (row-major reshape, NOT transpose)
    v -= cent[c * K_DIM + lane] * asum[n * K_DIM + lane];

    float ss = v * v;
#pragma unroll
    for (int o = 32; o > 0; o >>= 1) ss += __shfl_xor(ss, o);

    const float denom = fmaxf(sqrtf(ss), 1e-12f);
    out[off] = v / denom;
    if (lane == 0) ssb[w] = ss / (denom * denom);   // == clipped ratio, sums to gsum
}

// ---------------- gsum[n] = sum_c ssb[n][c] ----------------
__global__ __launch_bounds__(256) void k_gsum(const float* __restrict__ ssb,
                                              float* __restrict__ gsum) {
    const int n = blockIdx.x, t = threadIdx.x;
    float s = ssb[n * C_DIM + t] + ssb[n * C_DIM + t + 256];
    __shared__ float red[256];
    red[t] = s;
    __syncthreads();
    for (int o = 128; o > 0; o >>= 1) {
        if (t < o) red[t] += red[t + o];
        __syncthreads();
    }
    if (t == 0) gsum[n] = red[0];
}

// ---------------- final global L2 normalization ----------------
__global__ __launch_bounds__(256) void k_final(float* __restrict__ out,
                                               const float* __restrict__ gsum) {
    const size_t i = (size_t)blockIdx.x * 256 + threadIdx.x;  // 0 .. 2^20-1
    const int n = (int)(i >> 15);                             // C*K = 32768
    const float g = sqrtf(gsum[n]);
    out[i] = out[i] / fmaxf(g, 1e-12f);
}

extern "C" void kernel_launch(void* const* d_in, const int* in_sizes, int n_in,
                              void* d_out, int out_size, void* d_ws, size_t ws_size,
                              hipStream_t stream) {
    const float* x      = (const float*)d_in[0];  // (32,512,56,56)
    const float* cent   = (const float*)d_in[1];  // (64,512) flat
    const float* conv_w = (const float*)d_in[2];  // (64,512)
    const float* conv_b = (const float*)d_in[3];  // (64,)

    float* ws    = (float*)d_ws;
    float* wt    = ws;                                     // 32768
    float* a_t   = wt + 32768;                             // 32*3136*64
    float* asum  = a_t + (size_t)N_DIM * P_DIM * K_DIM;    // 2048
    float* apart = asum + 2048;                            // 32*14*64 = 28672
    float* gsum  = apart + 28672;                          // 32
    float* ssb   = gsum + 32;                              // 16384
    float* part  = ssb + 16384;                            // S * 1048576
    float* out   = (float*)d_out;

    const size_t base_f = (size_t)(part - ws);
    const size_t cxk = (size_t)N_DIM * C_DIM * K_DIM;      // 1048576
    int S = 14;
    if (ws_size < (base_f + 14 * cxk) * 4) S = 7;
    if (ws_size < (base_f + 7 * cxk) * 4) S = 2;
    const int pslice = P_DIM / S;

    hipLaunchKernelGGL(k_prep,   dim3(32),        dim3(256), 0, stream, conv_w, wt);
    hipLaunchKernelGGL(k_logits, dim3(49, 32),    dim3(64),  0, stream, x, wt, conv_b, a_t);
    hipLaunchKernelGGL(k_asum,   dim3(14, 32),    dim3(256), 0, stream, a_t, apart);
    hipLaunchKernelGGL(k_red,    dim3(8),         dim3(256), 0, stream, apart, asum);
    hipLaunchKernelGGL(k_gemm2,  dim3(4, 32, S),  dim3(128), 0, stream, x, a_t, part, pslice);
    if (S == 14)
        hipLaunchKernelGGL(k_intra<14>, dim3(4096), dim3(256), 0, stream, part, cent, asum, out, ssb);
    else if (S == 7)
        hipLaunchKernelGGL(k_intra<7>,  dim3(4096), dim3(256), 0, stream, part, cent, asum, out, ssb);
    else
        hipLaunchKernelGGL(k_intra<2>,  dim3(4096), dim3(256), 0, stream, part, cent, asum, out, ssb);
    hipLaunchKernelGGL(k_gsum,   dim3(32),        dim3(256), 0, stream, ssb, gsum);
    hipLaunchKernelGGL(k_final,  dim3(4096),      dim3(256), 0, stream, out, gsum);
}

// Round 5
// 519.755 us; speedup vs baseline: 1.4141x; 1.1883x over previous
//
#include <hip/hip_runtime.h>
#include <math.h>

#define N_DIM 32
#define C_DIM 512
#define K_DIM 64
#define P_DIM 3136
#define ABLK 49   // 3136/64 pixel-blocks for k_logits / asum partials

// ws layout (floats): wt 32768 | a_t 6422528 | asum 2048 | asum_part 100352 |
//                     gsum 32 | ssb 16384 | part S*1048576

// ---------------- prep: wt[c][k] = conv_w[k][c] ----------------
__global__ __launch_bounds__(256) void k_prep(const float* __restrict__ conv_w,
                                              float* __restrict__ wt) {
    const int b = blockIdx.x, t = threadIdx.x;
#pragma unroll
    for (int r = 0; r < 4; ++r) {
        int idx = b * 1024 + r * 256 + t;      // 0..32767
        int c = idx >> 6, k = idx & 63;
        wt[idx] = conv_w[k * C_DIM + c];
    }
}

// ---------------- GEMM1 + softmax + asum partials: a_t[n][p][k] ----------------
// HISTORY: r0 (LDS, 7xb32+2xb128/ch = ~50 LDS-cyc vs 28 VALU-share -> 31% cap);
// r2 (LDS-free, latency-bound); r3/r4 (lane=pixel + scalar-w s_loads -> SGPR
// spill to scratch: SGPR=112 capped, +23MB scratch writes, 20% VALU).
// v5: BOTH operands via LDS as per-lane VGPR float4s -> no scalar path, no
// SGPR pressure. Thread tile 8px x 8k (64 FMA/ch); lane = pxg*8+kg so the 8
// lanes of a pxg read the SAME b128 address (LDS broadcast, conflict-free):
// per channel 4 broadcast b128 (~23 LDS-cyc) vs 32 VALU-share-cyc -> VALU-bound.
// 1-wave blocks: no barriers (wave-internal DS ordering, validated r3/r4);
// 16-ch double-buffered chunks, reg-prefetch 2 chunks (~4k cyc) ahead of use.
// LDS 16KB -> all 1568 blocks resident (~6 waves/CU).
__global__ __launch_bounds__(64, 2) void k_logits(const float* __restrict__ x,
                                                  const float* __restrict__ wt,
                                                  const float* __restrict__ bias,
                                                  float* __restrict__ a_t,
                                                  float* __restrict__ asum_part) {
    __shared__ float xs[2][16][64];   // 8 KB  [buf][ch][px]
    __shared__ float wsh[2][16][64];  // 8 KB  [buf][ch][k]
    const int lane = threadIdx.x;     // 0..63
    const int n    = blockIdx.y;
    const int pblk = blockIdx.x;      // 0..48
    const int p0   = pblk * 64;
    const int kg   = lane & 7;        // k  = kg*8 .. +8   (lane bits 0..2)
    const int pxg  = lane >> 3;       // px = pxg*8 .. +8  (lane bits 3..5)

    float acc[8][8];
    {
        float4 b0 = *(const float4*)(bias + kg * 8);
        float4 b1 = *(const float4*)(bias + kg * 8 + 4);
        float br[8] = {b0.x, b0.y, b0.z, b0.w, b1.x, b1.y, b1.z, b1.w};
#pragma unroll
        for (int i = 0; i < 8; ++i)
#pragma unroll
            for (int j = 0; j < 8; ++j) acc[i][j] = br[j];
    }

    const float* xb = x + (size_t)n * C_DIM * P_DIM + p0;

    float4 xv[4], wv[4];
    // f = lane + 64*i  (0..255): ch = f>>4 (0..15), q = f&15 (float4 within row)
#define STAGE_LOAD(c0_) do {                                                      \
    _Pragma("unroll")                                                             \
    for (int i_ = 0; i_ < 4; ++i_) {                                              \
        int f_ = lane + 64 * i_;                                                  \
        xv[i_] = *(const float4*)(xb + (size_t)((c0_) + (f_ >> 4)) * P_DIM        \
                                     + (f_ & 15) * 4);                            \
        wv[i_] = *(const float4*)(wt + (size_t)(c0_) * K_DIM + f_ * 4);           \
    } } while (0)
#define STAGE_WRITE(buf_) do {                                                    \
    _Pragma("unroll")                                                             \
    for (int i_ = 0; i_ < 4; ++i_) {                                              \
        int f_ = lane + 64 * i_;                                                  \
        *(float4*)&xs[buf_][f_ >> 4][(f_ & 15) * 4]  = xv[i_];                    \
        *(float4*)&wsh[buf_][f_ >> 4][(f_ & 15) * 4] = wv[i_];                    \
    } } while (0)

    STAGE_LOAD(0);
    STAGE_WRITE(0);
    STAGE_LOAD(16);

    for (int cc = 0; cc < C_DIM; cc += 16) {
        const int buf = (cc >> 4) & 1;
        if (cc + 16 < C_DIM) {
            STAGE_WRITE(buf ^ 1);                    // regs(chunk cc+16) -> LDS
            if (cc + 32 < C_DIM) STAGE_LOAD(cc + 32);
        }
#pragma unroll
        for (int c = 0; c < 16; ++c) {
            float4 x0 = *(const float4*)&xs[buf][c][pxg * 8];      // broadcast
            float4 x1 = *(const float4*)&xs[buf][c][pxg * 8 + 4];  // (8 lanes/addr)
            float4 w0 = *(const float4*)&wsh[buf][c][kg * 8];
            float4 w1 = *(const float4*)&wsh[buf][c][kg * 8 + 4];
            float xr[8] = {x0.x, x0.y, x0.z, x0.w, x1.x, x1.y, x1.z, x1.w};
            float wr[8] = {w0.x, w0.y, w0.z, w0.w, w1.x, w1.y, w1.z, w1.w};
#pragma unroll
            for (int i = 0; i < 8; ++i)
#pragma unroll
                for (int j = 0; j < 8; ++j)
                    acc[i][j] = fmaf(xr[i], wr[j], acc[i][j]);
        }
    }
#undef STAGE_LOAD
#undef STAGE_WRITE

    // softmax per pixel: 64 k live in the 8 kg lanes sharing pxg (xor 1,2,4)
    float sk[8] = {0.f, 0.f, 0.f, 0.f, 0.f, 0.f, 0.f, 0.f};
#pragma unroll
    for (int i = 0; i < 8; ++i) {
        float m = acc[i][0];
#pragma unroll
        for (int j = 1; j < 8; ++j) m = fmaxf(m, acc[i][j]);
        m = fmaxf(m, __shfl_xor(m, 1));
        m = fmaxf(m, __shfl_xor(m, 2));
        m = fmaxf(m, __shfl_xor(m, 4));
        float e[8], s = 0.f;
#pragma unroll
        for (int j = 0; j < 8; ++j) { e[j] = __expf(acc[i][j] - m); s += e[j]; }
        s += __shfl_xor(s, 1);
        s += __shfl_xor(s, 2);
        s += __shfl_xor(s, 4);
        const float inv = 1.0f / s;
        float4 o0, o1;
        o0.x = e[0] * inv; o0.y = e[1] * inv; o0.z = e[2] * inv; o0.w = e[3] * inv;
        o1.x = e[4] * inv; o1.y = e[5] * inv; o1.z = e[6] * inv; o1.w = e[7] * inv;
        float* ap = a_t + ((size_t)n * P_DIM + p0 + pxg * 8 + i) * K_DIM + kg * 8;
        *(float4*)ap = o0;
        *(float4*)(ap + 4) = o1;
        sk[0] += o0.x; sk[1] += o0.y; sk[2] += o0.z; sk[3] += o0.w;
        sk[4] += o1.x; sk[5] += o1.y; sk[6] += o1.z; sk[7] += o1.w;
    }
    // reduce over pxg (lane bits 3,4,5); 1 wave -> direct store from lanes 0..7
#pragma unroll
    for (int j = 0; j < 8; ++j) {
        sk[j] += __shfl_xor(sk[j], 8);
        sk[j] += __shfl_xor(sk[j], 16);
        sk[j] += __shfl_xor(sk[j], 32);
    }
    if (pxg == 0) {   // lane == kg, holds k = kg*8+j totals over all 64 px
        float* pp = asum_part + ((size_t)n * ABLK + pblk) * K_DIM + kg * 8;
        float4 s0, s1;
        s0.x = sk[0]; s0.y = sk[1]; s0.z = sk[2]; s0.w = sk[3];
        s1.x = sk[4]; s1.y = sk[5]; s1.z = sk[6]; s1.w = sk[7];
        *(float4*)pp = s0;
        *(float4*)(pp + 4) = s1;
    }
}

// ---------------- asum[n][k] = sum_b asum_part[n][b][k] ----------------
__global__ __launch_bounds__(256) void k_red(const float* __restrict__ asum_part,
                                             float* __restrict__ asum) {
    const int idx = blockIdx.x * 256 + threadIdx.x;   // 0..2047
    const int n = idx >> 6, k = idx & 63;
    float s = 0.f;
#pragma unroll
    for (int b = 0; b < ABLK; ++b)
        s += asum_part[((size_t)n * ABLK + b) * K_DIM + k];
    asum[idx] = s;
}

// ---------------- GEMM2: part[s][n][c][k] = sum_{p in slice s} x[n][c][p]*a_t[n][p][k] ----
// block: 128c x 64k, 128 threads, 8x8/thread; plain stores (no atomics);
// register-prefetch double buffering over 16-p chunks.
__global__ __launch_bounds__(128) void k_gemm2(const float* __restrict__ x,
                                               const float* __restrict__ a_t,
                                               float* __restrict__ part,
                                               int pslice) {
    __shared__ float xs[16][132];   // [p][c], pad 128->132 (stores 2-way max)
    __shared__ float as[16][64];    // [p][k]
    const int tid = threadIdx.x;
    const int c0 = blockIdx.x * 128;
    const int n  = blockIdx.y;
    const int s  = blockIdx.z;
    const int p0 = s * pslice;
    const int tc = tid >> 3;        // 0..15 -> c = c0 + tc*8
    const int tk = tid & 7;         // 0..7  -> k = tk*8

    float acc[8][8];
#pragma unroll
    for (int i = 0; i < 8; ++i)
#pragma unroll
        for (int j = 0; j < 8; ++j) acc[i][j] = 0.f;

    const float* xb = x + ((size_t)n * C_DIM + c0) * P_DIM + p0;
    const float* ab = a_t + ((size_t)n * P_DIM + p0) * K_DIM;

    float4 xv[4], av[2];
#pragma unroll
    for (int i = 0; i < 4; ++i) {
        int f = tid + 128 * i;
        xv[i] = *(const float4*)(xb + (size_t)(f >> 2) * P_DIM + (f & 3) * 4);
    }
#pragma unroll
    for (int i = 0; i < 2; ++i) {
        int f = tid + 128 * i;
        av[i] = *(const float4*)(ab + (size_t)(f >> 4) * K_DIM + (f & 15) * 4);
    }

    for (int pb = 0; pb < pslice; pb += 16) {
        __syncthreads();
#pragma unroll
        for (int i = 0; i < 4; ++i) {
            int f = tid + 128 * i;
            int c = f >> 2, pe = (f & 3) * 4;
            xs[pe + 0][c] = xv[i].x;
            xs[pe + 1][c] = xv[i].y;
            xs[pe + 2][c] = xv[i].z;
            xs[pe + 3][c] = xv[i].w;
        }
#pragma unroll
        for (int i = 0; i < 2; ++i) {
            int f = tid + 128 * i;
            *(float4*)&as[f >> 4][(f & 15) * 4] = av[i];
        }
        __syncthreads();

        if (pb + 16 < pslice) {
            const float* xc = xb + pb + 16;
            const float* ac = ab + (size_t)(pb + 16) * K_DIM;
#pragma unroll
            for (int i = 0; i < 4; ++i) {
                int f = tid + 128 * i;
                xv[i] = *(const float4*)(xc + (size_t)(f >> 2) * P_DIM + (f & 3) * 4);
            }
#pragma unroll
            for (int i = 0; i < 2; ++i) {
                int f = tid + 128 * i;
                av[i] = *(const float4*)(ac + (size_t)(f >> 4) * K_DIM + (f & 15) * 4);
            }
        }

#pragma unroll 4
        for (int p = 0; p < 16; ++p) {
            float4 x0 = *(const float4*)&xs[p][tc * 8];
            float4 x1 = *(const float4*)&xs[p][tc * 8 + 4];
            float4 a0 = *(const float4*)&as[p][tk * 8];
            float4 a1 = *(const float4*)&as[p][tk * 8 + 4];
            float xr[8] = {x0.x, x0.y, x0.z, x0.w, x1.x, x1.y, x1.z, x1.w};
            float ar[8] = {a0.x, a0.y, a0.z, a0.w, a1.x, a1.y, a1.z, a1.w};
#pragma unroll
            for (int i = 0; i < 8; ++i)
#pragma unroll
                for (int j = 0; j < 8; ++j)
                    acc[i][j] = fmaf(xr[i], ar[j], acc[i][j]);
        }
    }

    float* po = part + (((size_t)s * N_DIM + n) * C_DIM + c0 + tc * 8) * K_DIM + tk * 8;
#pragma unroll
    for (int i = 0; i < 8; ++i) {
        float4 o0, o1;
        o0.x = acc[i][0]; o0.y = acc[i][1]; o0.z = acc[i][2]; o0.w = acc[i][3];
        o1.x = acc[i][4]; o1.y = acc[i][5]; o1.z = acc[i][6]; o1.w = acc[i][7];
        *(float4*)&po[(size_t)i * K_DIM] = o0;
        *(float4*)&po[(size_t)i * K_DIM + 4] = o1;
    }
}

// ---------------- slice-reduce + subtract + intra-norm over k; ss -> ssb (no atomics) ----
template <int S>
__global__ __launch_bounds__(256) void k_intra(const float* __restrict__ part,
                                               const float* __restrict__ cent,
                                               const float* __restrict__ asum,
                                               float* __restrict__ out,
                                               float* __restrict__ ssb) {
    const int w = (blockIdx.x * 256 + threadIdx.x) >> 6;  // (n,c) wave id
    const int lane = threadIdx.x & 63;
    const int n = w >> 9;
    const int c = w & 511;
    const size_t off = ((size_t)n * C_DIM + c) * K_DIM + lane;
    const size_t stride = (size_t)N_DIM * C_DIM * K_DIM;

    float v = 0.f;
#pragma unroll
    for (int s = 0; s < S; ++s) v += part[s * stride + off];
    // cent_r[c][k] = centroids_flat[c*64 + k] (row-major reshape, NOT transpose)
    v -= cent[c * K_DIM + lane] * asum[n * K_DIM + lane];

    float ss = v * v;
#pragma unroll
    for (int o = 32; o > 0; o >>= 1) ss += __shfl_xor(ss, o);

    const float denom = fmaxf(sqrtf(ss), 1e-12f);
    out[off] = v / denom;
    if (lane == 0) ssb[w] = ss / (denom * denom);   // == clipped ratio, sums to gsum
}

// ---------------- gsum[n] = sum_c ssb[n][c] ----------------
__global__ __launch_bounds__(256) void k_gsum(const float* __restrict__ ssb,
                                              float* __restrict__ gsum) {
    const int n = blockIdx.x, t = threadIdx.x;
    float s = ssb[n * C_DIM + t] + ssb[n * C_DIM + t + 256];
    __shared__ float red[256];
    red[t] = s;
    __syncthreads();
    for (int o = 128; o > 0; o >>= 1) {
        if (t < o) red[t] += red[t + o];
        __syncthreads();
    }
    if (t == 0) gsum[n] = red[0];
}

// ---------------- final global L2 normalization ----------------
__global__ __launch_bounds__(256) void k_final(float* __restrict__ out,
                                               const float* __restrict__ gsum) {
    const size_t i = (size_t)blockIdx.x * 256 + threadIdx.x;  // 0 .. 2^20-1
    const int n = (int)(i >> 15);                             // C*K = 32768
    const float g = sqrtf(gsum[n]);
    out[i] = out[i] / fmaxf(g, 1e-12f);
}

extern "C" void kernel_launch(void* const* d_in, const int* in_sizes, int n_in,
                              void* d_out, int out_size, void* d_ws, size_t ws_size,
                              hipStream_t stream) {
    const float* x      = (const float*)d_in[0];  // (32,512,56,56)
    const float* cent   = (const float*)d_in[1];  // (64,512) flat
    const float* conv_w = (const float*)d_in[2];  // (64,512)
    const float* conv_b = (const float*)d_in[3];  // (64,)

    float* ws    = (float*)d_ws;
    float* wt    = ws;                                     // 32768
    float* a_t   = wt + 32768;                             // 32*3136*64
    float* asum  = a_t + (size_t)N_DIM * P_DIM * K_DIM;    // 2048
    float* apart = asum + 2048;                            // 32*49*64 = 100352
    float* gsum  = apart + (size_t)N_DIM * ABLK * K_DIM;   // 32
    float* ssb   = gsum + 32;                              // 16384
    float* part  = ssb + 16384;                            // S * 1048576
    float* out   = (float*)d_out;

    const size_t base_f = (size_t)(part - ws);
    const size_t cxk = (size_t)N_DIM * C_DIM * K_DIM;      // 1048576
    int S = 14;
    if (ws_size < (base_f + 14 * cxk) * 4) S = 7;
    if (ws_size < (base_f + 7 * cxk) * 4) S = 2;
    const int pslice = P_DIM / S;

    hipLaunchKernelGGL(k_prep,   dim3(32),        dim3(256), 0, stream, conv_w, wt);
    hipLaunchKernelGGL(k_logits, dim3(ABLK, 32),  dim3(64),  0, stream, x, wt, conv_b, a_t, apart);
    hipLaunchKernelGGL(k_red,    dim3(8),         dim3(256), 0, stream, apart, asum);
    hipLaunchKernelGGL(k_gemm2,  dim3(4, 32, S),  dim3(128), 0, stream, x, a_t, part, pslice);
    if (S == 14)
        hipLaunchKernelGGL(k_intra<14>, dim3(4096), dim3(256), 0, stream, part, cent, asum, out, ssb);
    else if (S == 7)
        hipLaunchKernelGGL(k_intra<7>,  dim3(4096), dim3(256), 0, stream, part, cent, asum, out, ssb);
    else
        hipLaunchKernelGGL(k_intra<2>,  dim3(4096), dim3(256), 0, stream, part, cent, asum, out, ssb);
    hipLaunchKernelGGL(k_gsum,   dim3(32),        dim3(256), 0, stream, ssb, gsum);
    hipLaunchKernelGGL(k_final,  dim3(4096),      dim3(256), 0, stream, out, gsum);
}

// Round 6
// 503.691 us; speedup vs baseline: 1.4592x; 1.0319x over previous
//
#include <hip/hip_runtime.h>
#include <math.h>

#define N_DIM 32
#define C_DIM 512
#define K_DIM 64
#define P_DIM 3136
#define ABLK 49   // 3136/64 pixel-blocks for k_logits / asum partials

// ws layout (floats): wt 32768 | a_t 6422528 | asum 2048 | asum_part 100352 |
//                     gsum 32 | ssb 16384 | part S*1048576

// ---------------- prep: wt[c][k] = conv_w[k][c] ----------------
__global__ __launch_bounds__(256) void k_prep(const float* __restrict__ conv_w,
                                              float* __restrict__ wt) {
    const int b = blockIdx.x, t = threadIdx.x;
#pragma unroll
    for (int r = 0; r < 4; ++r) {
        int idx = b * 1024 + r * 256 + t;      // 0..32767
        int c = idx >> 6, k = idx & 63;
        wt[idx] = conv_w[k * C_DIM + c];
    }
}

// direct global->LDS DMA, 16B per lane, zero VGPR staging cost
__device__ __forceinline__ void gld_lds16(const float* g, void* l) {
    __builtin_amdgcn_global_load_lds(
        (const __attribute__((address_space(1))) void*)g,
        (__attribute__((address_space(3))) void*)l, 16, 0, 0);
}

// ---------------- GEMM1 + softmax + asum partials: a_t[n][p][k] ----------------
// HISTORY: r0 LDS-issue-bound (31% cap); r2 LDS-free latency-bound; r3/r4
// scalar-w SGPR-spill; r5 8px x 8k LDS-broadcast — structure right, but 32
// VGPRs of reg-staging pushed live set past the 128-VGPR step -> scratch
// spill (WRITE_SIZE 186MB vs 26MB needed) -> spill-traffic-bound at 196us.
// v6: staging via __builtin_amdgcn_global_load_lds (width 16): ZERO staging
// VGPRs -> live set ~95 -> no spill. Counted-vmcnt double buffer (issue
// chunk i+1's 8 loads; s_waitcnt vmcnt(8) before computing chunk i; never
// vmcnt(0) in-loop). LDS dest is LINEAR (uniform base + lane*16, rule-21:
// linear dest + per-lane global src + linear read). 1-wave blocks: no
// barriers; wave-internal ordering by explicit vmcnt/lgkmcnt.
// Compute: thread tile 8px x 8k; lane = pxg*8+kg; per channel 4 broadcast
// ds_read_b128 (8 lanes/addr, conflict-free) : 64 FMA.
__global__ __launch_bounds__(64, 2) void k_logits(const float* __restrict__ x,
                                                  const float* __restrict__ wt,
                                                  const float* __restrict__ bias,
                                                  float* __restrict__ a_t,
                                                  float* __restrict__ asum_part) {
    __shared__ __align__(16) float xs[2][16][64];   // 8 KB  [buf][ch][px]
    __shared__ __align__(16) float wsh[2][16][64];  // 8 KB  [buf][ch][k]
    const int lane = threadIdx.x;     // 0..63
    const int n    = blockIdx.y;
    const int pblk = blockIdx.x;      // 0..48
    const int p0   = pblk * 64;
    const int kg   = lane & 7;        // k  = kg*8 .. +8   (lane bits 0..2)
    const int pxg  = lane >> 3;       // px = pxg*8 .. +8  (lane bits 3..5)

    float acc[8][8];
    {
        float4 b0 = *(const float4*)(bias + kg * 8);
        float4 b1 = *(const float4*)(bias + kg * 8 + 4);
        float br[8] = {b0.x, b0.y, b0.z, b0.w, b1.x, b1.y, b1.z, b1.w};
#pragma unroll
        for (int i = 0; i < 8; ++i)
#pragma unroll
            for (int j = 0; j < 8; ++j) acc[i][j] = br[j];
    }

    const float* xb = x + (size_t)n * C_DIM * P_DIM + p0;

    // f = lane + 64*i (0..255): ch = f>>4 (0..15), q = f&15 (float4 in row).
    // LDS byte offset = f*16 = (i*1024) + lane*16 -> linear dest per load i.
#define STAGE(chk_, buf_) do {                                                    \
    const int c0_ = (chk_) * 16;                                                  \
    _Pragma("unroll")                                                             \
    for (int i_ = 0; i_ < 4; ++i_) {                                              \
        int f_ = lane + 64 * i_;                                                  \
        gld_lds16(xb + (size_t)(c0_ + (f_ >> 4)) * P_DIM + (f_ & 15) * 4,         \
                  (char*)&xs[buf_][0][0] + i_ * 1024);                            \
        gld_lds16(wt + (size_t)c0_ * K_DIM + f_ * 4,                              \
                  (char*)&wsh[buf_][0][0] + i_ * 1024);                           \
    } } while (0)

#define COMPUTE(buf_) do {                                                        \
    _Pragma("unroll")                                                             \
    for (int c_ = 0; c_ < 16; ++c_) {                                             \
        float4 x0 = *(const float4*)&xs[buf_][c_][pxg * 8];                       \
        float4 x1 = *(const float4*)&xs[buf_][c_][pxg * 8 + 4];                   \
        float4 w0 = *(const float4*)&wsh[buf_][c_][kg * 8];                       \
        float4 w1 = *(const float4*)&wsh[buf_][c_][kg * 8 + 4];                   \
        float xr[8] = {x0.x, x0.y, x0.z, x0.w, x1.x, x1.y, x1.z, x1.w};           \
        float wr[8] = {w0.x, w0.y, w0.z, w0.w, w1.x, w1.y, w1.z, w1.w};           \
        _Pragma("unroll")                                                         \
        for (int i_ = 0; i_ < 8; ++i_)                                            \
            _Pragma("unroll")                                                     \
            for (int j_ = 0; j_ < 8; ++j_)                                        \
                acc[i_][j_] = fmaf(xr[i_], wr[j_], acc[i_][j_]);                  \
    } } while (0)

    STAGE(0, 0);
    STAGE(1, 1);
    // 32 chunks of 16 channels; steady state: 8 loads (next chunk) in flight.
    for (int i = 0; i < 31; ++i) {
        asm volatile("s_waitcnt vmcnt(8)" ::: "memory");   // chunk i landed
        if (i & 1) COMPUTE(1); else COMPUTE(0);
        asm volatile("s_waitcnt lgkmcnt(0)" ::: "memory"); // buf reads retired
        if (i < 30) STAGE(i + 2, i & 1);                   // refill freed buf
    }
    asm volatile("s_waitcnt vmcnt(0)" ::: "memory");
    COMPUTE(1);                                            // chunk 31 (buf 1)
#undef STAGE
#undef COMPUTE

    // softmax per pixel: 64 k live in the 8 kg lanes sharing pxg (xor 1,2,4)
    float sk[8] = {0.f, 0.f, 0.f, 0.f, 0.f, 0.f, 0.f, 0.f};
#pragma unroll
    for (int i = 0; i < 8; ++i) {
        float m = acc[i][0];
#pragma unroll
        for (int j = 1; j < 8; ++j) m = fmaxf(m, acc[i][j]);
        m = fmaxf(m, __shfl_xor(m, 1));
        m = fmaxf(m, __shfl_xor(m, 2));
        m = fmaxf(m, __shfl_xor(m, 4));
        float e[8], s = 0.f;
#pragma unroll
        for (int j = 0; j < 8; ++j) { e[j] = __expf(acc[i][j] - m); s += e[j]; }
        s += __shfl_xor(s, 1);
        s += __shfl_xor(s, 2);
        s += __shfl_xor(s, 4);
        const float inv = 1.0f / s;
        float4 o0, o1;
        o0.x = e[0] * inv; o0.y = e[1] * inv; o0.z = e[2] * inv; o0.w = e[3] * inv;
        o1.x = e[4] * inv; o1.y = e[5] * inv; o1.z = e[6] * inv; o1.w = e[7] * inv;
        float* ap = a_t + ((size_t)n * P_DIM + p0 + pxg * 8 + i) * K_DIM + kg * 8;
        *(float4*)ap = o0;
        *(float4*)(ap + 4) = o1;
        sk[0] += o0.x; sk[1] += o0.y; sk[2] += o0.z; sk[3] += o0.w;
        sk[4] += o1.x; sk[5] += o1.y; sk[6] += o1.z; sk[7] += o1.w;
    }
    // reduce over pxg (lane bits 3,4,5); 1 wave -> direct store from lanes 0..7
#pragma unroll
    for (int j = 0; j < 8; ++j) {
        sk[j] += __shfl_xor(sk[j], 8);
        sk[j] += __shfl_xor(sk[j], 16);
        sk[j] += __shfl_xor(sk[j], 32);
    }
    if (pxg == 0) {   // lane == kg, holds k = kg*8+j totals over all 64 px
        float* pp = asum_part + ((size_t)n * ABLK + pblk) * K_DIM + kg * 8;
        float4 s0, s1;
        s0.x = sk[0]; s0.y = sk[1]; s0.z = sk[2]; s0.w = sk[3];
        s1.x = sk[4]; s1.y = sk[5]; s1.z = sk[6]; s1.w = sk[7];
        *(float4*)pp = s0;
        *(float4*)(pp + 4) = s1;
    }
}

// ---------------- asum[n][k] = sum_b asum_part[n][b][k] ----------------
__global__ __launch_bounds__(256) void k_red(const float* __restrict__ asum_part,
                                             float* __restrict__ asum) {
    const int idx = blockIdx.x * 256 + threadIdx.x;   // 0..2047
    const int n = idx >> 6, k = idx & 63;
    float s = 0.f;
#pragma unroll
    for (int b = 0; b < ABLK; ++b)
        s += asum_part[((size_t)n * ABLK + b) * K_DIM + k];
    asum[idx] = s;
}

// ---------------- GEMM2: part[s][n][c][k] = sum_{p in slice s} x[n][c][p]*a_t[n][p][k] ----
// block: 128c x 64k, 128 threads, 8x8/thread; plain stores (no atomics);
// register-prefetch double buffering over 16-p chunks.
__global__ __launch_bounds__(128) void k_gemm2(const float* __restrict__ x,
                                               const float* __restrict__ a_t,
                                               float* __restrict__ part,
                                               int pslice) {
    __shared__ float xs[16][132];   // [p][c], pad 128->132 (stores 2-way max)
    __shared__ float as[16][64];    // [p][k]
    const int tid = threadIdx.x;
    const int c0 = blockIdx.x * 128;
    const int n  = blockIdx.y;
    const int s  = blockIdx.z;
    const int p0 = s * pslice;
    const int tc = tid >> 3;        // 0..15 -> c = c0 + tc*8
    const int tk = tid & 7;         // 0..7  -> k = tk*8

    float acc[8][8];
#pragma unroll
    for (int i = 0; i < 8; ++i)
#pragma unroll
        for (int j = 0; j < 8; ++j) acc[i][j] = 0.f;

    const float* xb = x + ((size_t)n * C_DIM + c0) * P_DIM + p0;
    const float* ab = a_t + ((size_t)n * P_DIM + p0) * K_DIM;

    float4 xv[4], av[2];
#pragma unroll
    for (int i = 0; i < 4; ++i) {
        int f = tid + 128 * i;
        xv[i] = *(const float4*)(xb + (size_t)(f >> 2) * P_DIM + (f & 3) * 4);
    }
#pragma unroll
    for (int i = 0; i < 2; ++i) {
        int f = tid + 128 * i;
        av[i] = *(const float4*)(ab + (size_t)(f >> 4) * K_DIM + (f & 15) * 4);
    }

    for (int pb = 0; pb < pslice; pb += 16) {
        __syncthreads();
#pragma unroll
        for (int i = 0; i < 4; ++i) {
            int f = tid + 128 * i;
            int c = f >> 2, pe = (f & 3) * 4;
            xs[pe + 0][c] = xv[i].x;
            xs[pe + 1][c] = xv[i].y;
            xs[pe + 2][c] = xv[i].z;
            xs[pe + 3][c] = xv[i].w;
        }
#pragma unroll
        for (int i = 0; i < 2; ++i) {
            int f = tid + 128 * i;
            *(float4*)&as[f >> 4][(f & 15) * 4] = av[i];
        }
        __syncthreads();

        if (pb + 16 < pslice) {
            const float* xc = xb + pb + 16;
            const float* ac = ab + (size_t)(pb + 16) * K_DIM;
#pragma unroll
            for (int i = 0; i < 4; ++i) {
                int f = tid + 128 * i;
                xv[i] = *(const float4*)(xc + (size_t)(f >> 2) * P_DIM + (f & 3) * 4);
            }
#pragma unroll
            for (int i = 0; i < 2; ++i) {
                int f = tid + 128 * i;
                av[i] = *(const float4*)(ac + (size_t)(f >> 4) * K_DIM + (f & 15) * 4);
            }
        }

#pragma unroll 4
        for (int p = 0; p < 16; ++p) {
            float4 x0 = *(const float4*)&xs[p][tc * 8];
            float4 x1 = *(const float4*)&xs[p][tc * 8 + 4];
            float4 a0 = *(const float4*)&as[p][tk * 8];
            float4 a1 = *(const float4*)&as[p][tk * 8 + 4];
            float xr[8] = {x0.x, x0.y, x0.z, x0.w, x1.x, x1.y, x1.z, x1.w};
            float ar[8] = {a0.x, a0.y, a0.z, a0.w, a1.x, a1.y, a1.z, a1.w};
#pragma unroll
            for (int i = 0; i < 8; ++i)
#pragma unroll
                for (int j = 0; j < 8; ++j)
                    acc[i][j] = fmaf(xr[i], ar[j], acc[i][j]);
        }
    }

    float* po = part + (((size_t)s * N_DIM + n) * C_DIM + c0 + tc * 8) * K_DIM + tk * 8;
#pragma unroll
    for (int i = 0; i < 8; ++i) {
        float4 o0, o1;
        o0.x = acc[i][0]; o0.y = acc[i][1]; o0.z = acc[i][2]; o0.w = acc[i][3];
        o1.x = acc[i][4]; o1.y = acc[i][5]; o1.z = acc[i][6]; o1.w = acc[i][7];
        *(float4*)&po[(size_t)i * K_DIM] = o0;
        *(float4*)&po[(size_t)i * K_DIM + 4] = o1;
    }
}

// ---------------- slice-reduce + subtract + intra-norm over k; ss -> ssb (no atomics) ----
template <int S>
__global__ __launch_bounds__(256) void k_intra(const float* __restrict__ part,
                                               const float* __restrict__ cent,
                                               const float* __restrict__ asum,
                                               float* __restrict__ out,
                                               float* __restrict__ ssb) {
    const int w = (blockIdx.x * 256 + threadIdx.x) >> 6;  // (n,c) wave id
    const int lane = threadIdx.x & 63;
    const int n = w >> 9;
    const int c = w & 511;
    const size_t off = ((size_t)n * C_DIM + c) * K_DIM + lane;
    const size_t stride = (size_t)N_DIM * C_DIM * K_DIM;

    float v = 0.f;
#pragma unroll
    for (int s = 0; s < S; ++s) v += part[s * stride + off];
    // cent_r[c][k] = centroids_flat[c*64 + k] (row-major reshape, NOT transpose)
    v -= cent[c * K_DIM + lane] * asum[n * K_DIM + lane];

    float ss = v * v;
#pragma unroll
    for (int o = 32; o > 0; o >>= 1) ss += __shfl_xor(ss, o);

    const float denom = fmaxf(sqrtf(ss), 1e-12f);
    out[off] = v / denom;
    if (lane == 0) ssb[w] = ss / (denom * denom);   // == clipped ratio, sums to gsum
}

// ---------------- gsum[n] = sum_c ssb[n][c] ----------------
__global__ __launch_bounds__(256) void k_gsum(const float* __restrict__ ssb,
                                              float* __restrict__ gsum) {
    const int n = blockIdx.x, t = threadIdx.x;
    float s = ssb[n * C_DIM + t] + ssb[n * C_DIM + t + 256];
    __shared__ float red[256];
    red[t] = s;
    __syncthreads();
    for (int o = 128; o > 0; o >>= 1) {
        if (t < o) red[t] += red[t + o];
        __syncthreads();
    }
    if (t == 0) gsum[n] = red[0];
}

// ---------------- final global L2 normalization ----------------
__global__ __launch_bounds__(256) void k_final(float* __restrict__ out,
                                               const float* __restrict__ gsum) {
    const size_t i = (size_t)blockIdx.x * 256 + threadIdx.x;  // 0 .. 2^20-1
    const int n = (int)(i >> 15);                             // C*K = 32768
    const float g = sqrtf(gsum[n]);
    out[i] = out[i] / fmaxf(g, 1e-12f);
}

extern "C" void kernel_launch(void* const* d_in, const int* in_sizes, int n_in,
                              void* d_out, int out_size, void* d_ws, size_t ws_size,
                              hipStream_t stream) {
    const float* x      = (const float*)d_in[0];  // (32,512,56,56)
    const float* cent   = (const float*)d_in[1];  // (64,512) flat
    const float* conv_w = (const float*)d_in[2];  // (64,512)
    const float* conv_b = (const float*)d_in[3];  // (64,)

    float* ws    = (float*)d_ws;
    float* wt    = ws;                                     // 32768
    float* a_t   = wt + 32768;                             // 32*3136*64
    float* asum  = a_t + (size_t)N_DIM * P_DIM * K_DIM;    // 2048
    float* apart = asum + 2048;                            // 32*49*64 = 100352
    float* gsum  = apart + (size_t)N_DIM * ABLK * K_DIM;   // 32
    float* ssb   = gsum + 32;                              // 16384
    float* part  = ssb + 16384;                            // S * 1048576
    float* out   = (float*)d_out;

    const size_t base_f = (size_t)(part - ws);
    const size_t cxk = (size_t)N_DIM * C_DIM * K_DIM;      // 1048576
    int S = 14;
    if (ws_size < (base_f + 14 * cxk) * 4) S = 7;
    if (ws_size < (base_f + 7 * cxk) * 4) S = 2;
    const int pslice = P_DIM / S;

    hipLaunchKernelGGL(k_prep,   dim3(32),        dim3(256), 0, stream, conv_w, wt);
    hipLaunchKernelGGL(k_logits, dim3(ABLK, 32),  dim3(64),  0, stream, x, wt, conv_b, a_t, apart);
    hipLaunchKernelGGL(k_red,    dim3(8),         dim3(256), 0, stream, apart, asum);
    hipLaunchKernelGGL(k_gemm2,  dim3(4, 32, S),  dim3(128), 0, stream, x, a_t, part, pslice);
    if (S == 14)
        hipLaunchKernelGGL(k_intra<14>, dim3(4096), dim3(256), 0, stream, part, cent, asum, out, ssb);
    else if (S == 7)
        hipLaunchKernelGGL(k_intra<7>,  dim3(4096), dim3(256), 0, stream, part, cent, asum, out, ssb);
    else
        hipLaunchKernelGGL(k_intra<2>,  dim3(4096), dim3(256), 0, stream, part, cent, asum, out, ssb);
    hipLaunchKernelGGL(k_gsum,   dim3(32),        dim3(256), 0, stream, ssb, gsum);
    hipLaunchKernelGGL(k_final,  dim3(4096),      dim3(256), 0, stream, out, gsum);
}